// Round 12
// baseline (954.965 us; speedup 1.0000x reference)
//
#include <hip/hip_runtime.h>
#include <hip/hip_bf16.h>

// Problem constants
#define NB   64      // batch N
#define TT   12      // T
#define VV   256     // V (vertices)
#define CIN  64
#define COUT 64
#define VSQ  65536   // V*V

typedef float f32x4 __attribute__((ext_vector_type(4)));

// ---------------------------------------------------------------------------
// ATTRIBUTION ROUND: exact R7 kernels (best config, 631 us), but K2 is
// launched TWICE (identical writes -> identical output, deterministic).
// dur_us = K1 + 2*K2 + K3  =>  K2 = dur_us - 631.
// ---------------------------------------------------------------------------

// K1: y[n,o,t,v] = sum_c x[n,c,t,v] * conv_w[o,c] + conv_b[o]
__global__ __launch_bounds__(256) void k1_conv(
    const float* __restrict__ x, const float* __restrict__ w,
    const float* __restrict__ b, float* __restrict__ y)
{
    const int nt = blockIdx.x;
    const int n  = nt / TT;
    const int t  = nt % TT;
    const int v  = threadIdx.x;

    const float* xp = x + ((long)n * CIN * TT + t) * VV + v;
    float xv[CIN];
    #pragma unroll 8
    for (int c = 0; c < CIN; ++c)
        xv[c] = xp[(long)c * TT * VV];          // coalesced

    float* yp = y + ((long)n * COUT * TT + t) * VV + v;

    for (int o0 = 0; o0 < COUT; o0 += 16) {
        float acc[16];
        #pragma unroll
        for (int i = 0; i < 16; ++i) acc[i] = b[o0 + i];
        #pragma unroll 8
        for (int c = 0; c < CIN; ++c) {
            const float xc = xv[c];
            #pragma unroll
            for (int i = 0; i < 16; ++i)
                acc[i] += w[(o0 + i) * CIN + c] * xc;   // uniform -> s_load
        }
        #pragma unroll
        for (int i = 0; i < 16; ++i)
            yp[(long)(o0 + i) * TT * VV] = acc[i];
    }
}

// K2 (R7 occupancy-first variant): 1 position/thread, o-chunks of 8,
// nontemporal stores, launch_bounds(256,5).
__global__ __launch_bounds__(256, 5) void k2_mlp(
    const float* __restrict__ A,
    const float* __restrict__ w1, const float* __restrict__ b1,
    const float* __restrict__ w2, const float* __restrict__ b2,
    const float* __restrict__ w3, const float* __restrict__ b3,
    float* __restrict__ Aw)
{
    const long idx = (long)blockIdx.x * 256 + threadIdx.x;  // n*VSQ + pos
    const int  n   = (int)(idx >> 16);
    const int  rem = (int)(idx & (VSQ - 1));

    const float* ap = A + ((long)n * 8 << 16) + rem;
    float f[7];
    #pragma unroll
    for (int c = 0; c < 7; ++c) f[c] = ap[(long)c << 16];
    const float m = ap[(long)7 << 16];

    float h1[16];
    #pragma unroll
    for (int o = 0; o < 16; ++o) {
        float acc = b1[o];
        #pragma unroll
        for (int k = 0; k < 7; ++k) acc += w1[o * 7 + k] * f[k];   // uniform
        h1[o] = fmaxf(acc, 0.f);
    }

    float h2[32];
    #pragma unroll
    for (int o = 0; o < 32; ++o) {
        float acc = b2[o];
        #pragma unroll
        for (int k = 0; k < 16; ++k) acc += w2[o * 16 + k] * h1[k]; // uniform
        h2[o] = fmaxf(acc, 0.f);
    }

    float* op = Aw + ((long)n * COUT << 16) + rem;
    for (int o0 = 0; o0 < 64; o0 += 8) {
        float acc[8];
        #pragma unroll
        for (int i = 0; i < 8; ++i) acc[i] = b3[o0 + i];
        #pragma unroll
        for (int k = 0; k < 32; ++k) {
            #pragma unroll
            for (int i = 0; i < 8; ++i)
                acc[i] += w3[(o0 + i) * 32 + k] * h2[k];            // uniform
        }
        #pragma unroll
        for (int i = 0; i < 8; ++i)
            __builtin_nontemporal_store(fmaxf(acc[i], 0.f) * m,
                                        op + ((long)(o0 + i) << 16));
    }
}

// K3 (R7): block = (n, c-quad), 48 KB LDS y tiles, nt f32x4 Aw loads.
__global__ __launch_bounds__(256) void k3_einsum(
    const float* __restrict__ Aw, const float* __restrict__ y,
    float* __restrict__ out)
{
    __shared__ float ys[4][TT][VV];

    const int n   = blockIdx.x >> 4;
    const int c0  = (blockIdx.x & 15) * 4;
    const int tid = threadIdx.x;
    const int cq  = tid >> 6;
    const int w4  = (tid & 63) * 4;

    {
        const float* src = y + ((long)(n * COUT + c0) * TT) * VV;
        float* dst = &ys[0][0][0];
        #pragma unroll
        for (int it = 0; it < 12; ++it) {
            const int idx = tid + it * 256;
            *reinterpret_cast<float4*>(dst + idx * 4) =
                *reinterpret_cast<const float4*>(src + idx * 4);
        }
    }
    __syncthreads();

    const float* awp = Aw + (((long)(n * COUT + c0 + cq)) << 16) + w4;
    float4 acc[TT];
    #pragma unroll
    for (int t = 0; t < TT; ++t) acc[t] = make_float4(0.f, 0.f, 0.f, 0.f);

    for (int v0 = 0; v0 < VV; v0 += 4) {
        float4 xs[TT];
        #pragma unroll
        for (int t = 0; t < TT; ++t)
            xs[t] = *reinterpret_cast<const float4*>(&ys[cq][t][v0]);

        const f32x4 aw0 = __builtin_nontemporal_load(
            reinterpret_cast<const f32x4*>(awp + (long)(v0 + 0) * VV));
        const f32x4 aw1 = __builtin_nontemporal_load(
            reinterpret_cast<const f32x4*>(awp + (long)(v0 + 1) * VV));
        const f32x4 aw2 = __builtin_nontemporal_load(
            reinterpret_cast<const f32x4*>(awp + (long)(v0 + 2) * VV));
        const f32x4 aw3 = __builtin_nontemporal_load(
            reinterpret_cast<const f32x4*>(awp + (long)(v0 + 3) * VV));

        #pragma unroll
        for (int t = 0; t < TT; ++t) {
            acc[t].x += xs[t].x * aw0.x + xs[t].y * aw1.x + xs[t].z * aw2.x + xs[t].w * aw3.x;
            acc[t].y += xs[t].x * aw0.y + xs[t].y * aw1.y + xs[t].z * aw2.y + xs[t].w * aw3.y;
            acc[t].z += xs[t].x * aw0.z + xs[t].y * aw1.z + xs[t].z * aw2.z + xs[t].w * aw3.z;
            acc[t].w += xs[t].x * aw0.w + xs[t].y * aw1.w + xs[t].z * aw2.w + xs[t].w * aw3.w;
        }
    }

    float* op = out + ((long)(n * COUT + c0 + cq) * TT) * VV + w4;
    #pragma unroll
    for (int t = 0; t < TT; ++t)
        *reinterpret_cast<float4*>(op + t * VV) = acc[t];
}

// ---------------------------------------------------------------------------
extern "C" void kernel_launch(void* const* d_in, const int* in_sizes, int n_in,
                              void* d_out, int out_size, void* d_ws, size_t ws_size,
                              hipStream_t stream)
{
    const float* x      = (const float*)d_in[0];
    const float* A      = (const float*)d_in[1];
    const float* conv_w = (const float*)d_in[2];
    const float* conv_b = (const float*)d_in[3];
    const float* w1     = (const float*)d_in[4];
    const float* b1     = (const float*)d_in[5];
    const float* w2     = (const float*)d_in[6];
    const float* b2     = (const float*)d_in[7];
    const float* w3     = (const float*)d_in[8];
    const float* b3     = (const float*)d_in[9];

    float* out = (float*)d_out;                                  // (64,64,12,256)
    float* Aw  = (float*)d_out + (long)NB * COUT * TT * VV;      // (64,64,256,256)
    const size_t y_bytes = (size_t)NB * COUT * TT * VV * sizeof(float);

    float* y = (ws_size >= y_bytes) ? (float*)d_ws : out;        // k3 handles alias

    // K1: conv -> y
    k1_conv<<<NB * TT, 256, 0, stream>>>(x, conv_w, conv_b, y);

    // K2: MLP + mask -> Aw ... TWICE (identical writes; attribution probe:
    // dur_us = K1 + 2*K2 + K3, so K2 = dur_us - 631)
    k2_mlp<<<(NB * VSQ) / 256, 256, 0, stream>>>(A, w1, b1, w2, b2, w3, b3, Aw);
    k2_mlp<<<(NB * VSQ) / 256, 256, 0, stream>>>(A, w1, b1, w2, b2, w3, b3, Aw);

    // K3: einsum (in-place safe if y == out)
    k3_einsum<<<NB * (COUT / 4), 256, 0, stream>>>(Aw, y, out);
}

// Round 13
// 670.053 us; speedup vs baseline: 1.4252x; 1.4252x over previous
//
#include <hip/hip_runtime.h>
#include <hip/hip_bf16.h>

// Problem constants
#define NB   64      // batch N
#define TT   12      // T
#define VV   256     // V (vertices)
#define CIN  64
#define COUT 64
#define VSQ  65536   // V*V

typedef float f32x4 __attribute__((ext_vector_type(4)));
typedef float f32x2 __attribute__((ext_vector_type(2)));
using s16x8 = __attribute__((ext_vector_type(8))) short;   // 8 bf16 (4 VGPRs)

__device__ __forceinline__ unsigned short f2bf(float f) {
    union { __hip_bfloat16 h; unsigned short u; } cv;
    cv.h = __float2bfloat16(f);          // RNE
    return cv.u;
}

// ---------------------------------------------------------------------------
// K1: y[n,o,t,v] = sum_c x[n,c,t,v] * conv_w[o,c] + conv_b[o]
// block = (n*T + t), 256 threads (thread = v). Proven ~20 us (BW floor).
// ---------------------------------------------------------------------------
__global__ __launch_bounds__(256) void k1_conv(
    const float* __restrict__ x, const float* __restrict__ w,
    const float* __restrict__ b, float* __restrict__ y)
{
    const int nt = blockIdx.x;
    const int n  = nt / TT;
    const int t  = nt % TT;
    const int v  = threadIdx.x;

    const float* xp = x + ((long)n * CIN * TT + t) * VV + v;
    float xv[CIN];
    #pragma unroll 8
    for (int c = 0; c < CIN; ++c)
        xv[c] = xp[(long)c * TT * VV];          // coalesced

    float* yp = y + ((long)n * COUT * TT + t) * VV + v;

    for (int o0 = 0; o0 < COUT; o0 += 16) {
        float acc[16];
        #pragma unroll
        for (int i = 0; i < 16; ++i) acc[i] = b[o0 + i];
        #pragma unroll 8
        for (int c = 0; c < CIN; ++c) {
            const float xc = xv[c];
            #pragma unroll
            for (int i = 0; i < 16; ++i)
                acc[i] += w[(o0 + i) * CIN + c] * xc;   // uniform -> s_load
        }
        #pragma unroll
        for (int i = 0; i < 16; ++i)
            yp[(long)(o0 + i) * TT * VV] = acc[i];
    }
}

// ---------------------------------------------------------------------------
// K2 v3: MFMA layer-3 with SWAPPED operands (D = w3 . h2, M=c, N=pos).
// R12 attribution: K2=324us. R7 variant = coalesced stores but ~280us
// VALU/weight-supply; R10 variant = ~40us VALU but scatter stores (C-layout
// col=lane&15 was c -> 16B chunks 256KB apart). Swapping the mfma operands
// makes col=lane&15 = POS: stores become 4x64B coalesced segments while
// keeping the MLP's heavy layer on the matrix pipe. Fragments are
// byte-identical to R10's verified ones (A-frag row-idx=lc <-> old w3 frag;
// B-frag col-idx=lc <-> old afrag) -- only arg order + store/bias indexing
// change. Expect: VALU ~40us overlapped with the 1.07GB write stream (~190).
// ---------------------------------------------------------------------------
__global__ __launch_bounds__(256) void k2_mlp(
    const float* __restrict__ A,
    const float* __restrict__ w1, const float* __restrict__ b1,
    const float* __restrict__ w2, const float* __restrict__ b2,
    const float* __restrict__ w3, const float* __restrict__ b3,
    float* __restrict__ Aw)
{
    __shared__ unsigned int afrag[16 * 256];   // 16 KiB B-fragments (h2)
    __shared__ float ms[256];                  // mask per position

    const int  tid  = threadIdx.x;
    const long gpos = (long)blockIdx.x * 256;      // n*VSQ + rem0
    const int  n    = (int)(gpos >> 16);
    const int  rem0 = (int)(gpos & (VSQ - 1));

    // ---------------- phase 1: h2 for position rem0+tid (R10-verified) -----
    {
        const float* ap = A + ((long)n * 8 << 16) + rem0 + tid;
        float f[7];
        #pragma unroll
        for (int c = 0; c < 7; ++c) f[c] = ap[(long)c << 16];   // coalesced
        ms[tid] = ap[(long)7 << 16];

        float h1[16];
        #pragma unroll
        for (int o = 0; o < 16; ++o) {
            float s = b1[o];
            #pragma unroll
            for (int k = 0; k < 7; ++k) s += w1[o * 7 + k] * f[k];   // uniform
            h1[o] = fmaxf(s, 0.f);
        }
        float h2[32];
        #pragma unroll
        for (int o = 0; o < 32; ++o) {
            float s = b2[o];
            #pragma unroll
            for (int k = 0; k < 16; ++k) s += w2[o * 16 + k] * h1[k]; // uniform
            h2[o] = fmaxf(s, 0.f);
        }

        const int m = tid >> 4;        // pos-tile
        const int r = tid & 15;        // row (col for B-frag) within tile
        #pragma unroll
        for (int kk = 0; kk < 16; ++kk) {   // bf16 pair (k=2kk, 2kk+1)
            const unsigned int pr = (unsigned int)f2bf(h2[2 * kk])
                                  | ((unsigned int)f2bf(h2[2 * kk + 1]) << 16);
            afrag[m * 256 + (kk >> 2) * 64 + r * 4 + (kk & 3)] = pr;
        }
    }
    __syncthreads();

    // ---------------- phase 2: layer 3, swapped-operand MFMA ----------------
    const int lane = tid & 63;
    const int wave = tid >> 6;
    const int lc   = lane & 15;
    const int lq   = lane >> 4;

    // A-operand: w3 fragments per c-tile (mt). Lane l holds A[row=lc][k=lq*8+i]
    // = w3[mt*16+lc][lq*8+i] -- same bytes as R10's B-frag.
    s16x8 wfr[4];
    f32x4 biasv[4];     // C-init: row = c = mt*16 + lq*4 + u
    #pragma unroll
    for (int mt = 0; mt < 4; ++mt) {
        const float* wr = w3 + (mt * 16 + lc) * 32 + lq * 8;
        s16x8 wf;
        #pragma unroll
        for (int i = 0; i < 8; ++i) wf[i] = (short)f2bf(wr[i]);
        wfr[mt] = wf;
        #pragma unroll
        for (int u = 0; u < 4; ++u) biasv[mt][u] = b3[mt * 16 + lq * 4 + u];
    }

    float* awbase = Aw + ((long)n * COUT << 16) + rem0;

    #pragma unroll
    for (int j = 0; j < 4; ++j) {
        const int pt  = wave * 4 + j;                  // pos-tile
        const s16x8 pfr = *reinterpret_cast<const s16x8*>(&afrag[pt * 256 + lane * 4]);
        const int   pos = pt * 16 + lc;                // col = lane&15 = position
        const float mf  = ms[pos];
        #pragma unroll
        for (int mt = 0; mt < 4; ++mt) {
            f32x4 a = biasv[mt];
            a = __builtin_amdgcn_mfma_f32_16x16x32_bf16(wfr[mt], pfr, a, 0, 0, 0);
            #pragma unroll
            for (int u = 0; u < 4; ++u) {
                const int c = mt * 16 + lq * 4 + u;    // row = c
                __builtin_nontemporal_store(fmaxf(a[u], 0.f) * mf,
                                            awbase + ((long)c << 16) + pos);
            }
        }
    }
}

// ---------------------------------------------------------------------------
// K3 v2: R7 structure, v-unroll 2 (xs as f32x2) to cut VGPR ~130 -> ~105,
// __launch_bounds__(256,4) -> 4 waves/SIMD (16/CU vs 12). Same VMEM count
// (f32x4 Aw loads), same DS cycles (b64 ~6cyc x2 = b128 ~12cyc). In-place
// safe (reads of y finish before barrier; writes after).
// ---------------------------------------------------------------------------
__global__ __launch_bounds__(256, 4) void k3_einsum(
    const float* __restrict__ Aw, const float* __restrict__ y,
    float* __restrict__ out)
{
    __shared__ float ys[4][TT][VV];     // 48 KiB

    const int n   = blockIdx.x >> 4;
    const int c0  = (blockIdx.x & 15) * 4;
    const int tid = threadIdx.x;
    const int cq  = tid >> 6;           // wave-uniform
    const int w4  = (tid & 63) * 4;

    {
        const float* src = y + ((long)(n * COUT + c0) * TT) * VV;
        float* dst = &ys[0][0][0];
        #pragma unroll
        for (int it = 0; it < 12; ++it) {
            const int idx = tid + it * 256;
            *reinterpret_cast<float4*>(dst + idx * 4) =
                *reinterpret_cast<const float4*>(src + idx * 4);
        }
    }
    __syncthreads();

    const float* awp = Aw + (((long)(n * COUT + c0 + cq)) << 16) + w4;
    f32x4 acc[TT];
    #pragma unroll
    for (int t = 0; t < TT; ++t) acc[t] = (f32x4)(0.f);

    for (int v0 = 0; v0 < VV; v0 += 2) {
        f32x2 xs[TT];
        #pragma unroll
        for (int t = 0; t < TT; ++t)
            xs[t] = *reinterpret_cast<const f32x2*>(&ys[cq][t][v0]);

        const f32x4 aw0 = __builtin_nontemporal_load(
            reinterpret_cast<const f32x4*>(awp + (long)(v0 + 0) * VV));
        const f32x4 aw1 = __builtin_nontemporal_load(
            reinterpret_cast<const f32x4*>(awp + (long)(v0 + 1) * VV));

        #pragma unroll
        for (int t = 0; t < TT; ++t)
            acc[t] += xs[t].x * aw0 + xs[t].y * aw1;
    }

    float* op = out + ((long)(n * COUT + c0 + cq) * TT) * VV + w4;
    #pragma unroll
    for (int t = 0; t < TT; ++t)
        *reinterpret_cast<f32x4*>(op + t * VV) = acc[t];
}

// ---------------------------------------------------------------------------
extern "C" void kernel_launch(void* const* d_in, const int* in_sizes, int n_in,
                              void* d_out, int out_size, void* d_ws, size_t ws_size,
                              hipStream_t stream)
{
    const float* x      = (const float*)d_in[0];
    const float* A      = (const float*)d_in[1];
    const float* conv_w = (const float*)d_in[2];
    const float* conv_b = (const float*)d_in[3];
    const float* w1     = (const float*)d_in[4];
    const float* b1     = (const float*)d_in[5];
    const float* w2     = (const float*)d_in[6];
    const float* b2     = (const float*)d_in[7];
    const float* w3     = (const float*)d_in[8];
    const float* b3     = (const float*)d_in[9];

    float* out = (float*)d_out;                                  // (64,64,12,256)
    float* Aw  = (float*)d_out + (long)NB * COUT * TT * VV;      // (64,64,256,256)
    const size_t y_bytes = (size_t)NB * COUT * TT * VV * sizeof(float);

    float* y = (ws_size >= y_bytes) ? (float*)d_ws : out;        // k3 handles alias

    // K1: conv -> y
    k1_conv<<<NB * TT, 256, 0, stream>>>(x, conv_w, conv_b, y);

    // K2: MLP + mask -> Aw (swapped-operand MFMA, coalesced stores)
    k2_mlp<<<(NB * VSQ) / 256, 256, 0, stream>>>(A, w1, b1, w2, b2, w3, b3, Aw);

    // K3: einsum (in-place safe if y == out)
    k3_einsum<<<NB * (COUT / 4), 256, 0, stream>>>(Aw, y, out);
}

// Round 14
// 661.069 us; speedup vs baseline: 1.4446x; 1.0136x over previous
//
#include <hip/hip_runtime.h>
#include <hip/hip_bf16.h>

// Problem constants
#define NB   64      // batch N
#define TT   12      // T
#define VV   256     // V (vertices)
#define CIN  64
#define COUT 64
#define VSQ  65536   // V*V

typedef float f32x4 __attribute__((ext_vector_type(4)));
using s16x8 = __attribute__((ext_vector_type(8))) short;   // 8 bf16 (4 VGPRs)

__device__ __forceinline__ unsigned short f2bf(float f) {
    union { __hip_bfloat16 h; unsigned short u; } cv;
    cv.h = __float2bfloat16(f);          // RNE
    return cv.u;
}

// ---------------------------------------------------------------------------
// K1: y[n,o,t,v] = sum_c x[n,c,t,v] * conv_w[o,c] + conv_b[o]
// block = (n*T + t), 256 threads (thread = v). Proven ~20 us (BW floor).
// ---------------------------------------------------------------------------
__global__ __launch_bounds__(256) void k1_conv(
    const float* __restrict__ x, const float* __restrict__ w,
    const float* __restrict__ b, float* __restrict__ y)
{
    const int nt = blockIdx.x;
    const int n  = nt / TT;
    const int t  = nt % TT;
    const int v  = threadIdx.x;

    const float* xp = x + ((long)n * CIN * TT + t) * VV + v;
    float xv[CIN];
    #pragma unroll 8
    for (int c = 0; c < CIN; ++c)
        xv[c] = xp[(long)c * TT * VV];          // coalesced

    float* yp = y + ((long)n * COUT * TT + t) * VV + v;

    for (int o0 = 0; o0 < COUT; o0 += 16) {
        float acc[16];
        #pragma unroll
        for (int i = 0; i < 16; ++i) acc[i] = b[o0 + i];
        #pragma unroll 8
        for (int c = 0; c < CIN; ++c) {
            const float xc = xv[c];
            #pragma unroll
            for (int i = 0; i < 16; ++i)
                acc[i] += w[(o0 + i) * CIN + c] * xc;   // uniform -> s_load
        }
        #pragma unroll
        for (int i = 0; i < 16; ++i)
            yp[(long)(o0 + i) * TT * VV] = acc[i];
    }
}

// ---------------------------------------------------------------------------
// K2 (R13 swapped-operand MFMA, UNCHANGED for attribution):
// D = w3 . h2 (M=c, N=pos); col=lane&15 = pos -> 4x64B-segment stores;
// MLP heavy layer on matrix pipe (VALU ~40us). K2_sw = dur_us - 307.
// ---------------------------------------------------------------------------
__global__ __launch_bounds__(256) void k2_mlp(
    const float* __restrict__ A,
    const float* __restrict__ w1, const float* __restrict__ b1,
    const float* __restrict__ w2, const float* __restrict__ b2,
    const float* __restrict__ w3, const float* __restrict__ b3,
    float* __restrict__ Aw)
{
    __shared__ unsigned int afrag[16 * 256];   // 16 KiB B-fragments (h2)
    __shared__ float ms[256];                  // mask per position

    const int  tid  = threadIdx.x;
    const long gpos = (long)blockIdx.x * 256;      // n*VSQ + rem0
    const int  n    = (int)(gpos >> 16);
    const int  rem0 = (int)(gpos & (VSQ - 1));

    // ---------------- phase 1: h2 for position rem0+tid ----------------
    {
        const float* ap = A + ((long)n * 8 << 16) + rem0 + tid;
        float f[7];
        #pragma unroll
        for (int c = 0; c < 7; ++c) f[c] = ap[(long)c << 16];   // coalesced
        ms[tid] = ap[(long)7 << 16];

        float h1[16];
        #pragma unroll
        for (int o = 0; o < 16; ++o) {
            float s = b1[o];
            #pragma unroll
            for (int k = 0; k < 7; ++k) s += w1[o * 7 + k] * f[k];   // uniform
            h1[o] = fmaxf(s, 0.f);
        }
        float h2[32];
        #pragma unroll
        for (int o = 0; o < 32; ++o) {
            float s = b2[o];
            #pragma unroll
            for (int k = 0; k < 16; ++k) s += w2[o * 16 + k] * h1[k]; // uniform
            h2[o] = fmaxf(s, 0.f);
        }

        const int m = tid >> 4;        // pos-tile
        const int r = tid & 15;        // col within tile
        #pragma unroll
        for (int kk = 0; kk < 16; ++kk) {
            const unsigned int pr = (unsigned int)f2bf(h2[2 * kk])
                                  | ((unsigned int)f2bf(h2[2 * kk + 1]) << 16);
            afrag[m * 256 + (kk >> 2) * 64 + r * 4 + (kk & 3)] = pr;
        }
    }
    __syncthreads();

    // ---------------- phase 2: layer 3, swapped-operand MFMA ----------------
    const int lane = tid & 63;
    const int wave = tid >> 6;
    const int lc   = lane & 15;
    const int lq   = lane >> 4;

    s16x8 wfr[4];
    f32x4 biasv[4];
    #pragma unroll
    for (int mt = 0; mt < 4; ++mt) {
        const float* wr = w3 + (mt * 16 + lc) * 32 + lq * 8;
        s16x8 wf;
        #pragma unroll
        for (int i = 0; i < 8; ++i) wf[i] = (short)f2bf(wr[i]);
        wfr[mt] = wf;
        #pragma unroll
        for (int u = 0; u < 4; ++u) biasv[mt][u] = b3[mt * 16 + lq * 4 + u];
    }

    float* awbase = Aw + ((long)n * COUT << 16) + rem0;

    #pragma unroll
    for (int j = 0; j < 4; ++j) {
        const int pt  = wave * 4 + j;
        const s16x8 pfr = *reinterpret_cast<const s16x8*>(&afrag[pt * 256 + lane * 4]);
        const int   pos = pt * 16 + lc;
        const float mf  = ms[pos];
        #pragma unroll
        for (int mt = 0; mt < 4; ++mt) {
            f32x4 a = biasv[mt];
            a = __builtin_amdgcn_mfma_f32_16x16x32_bf16(wfr[mt], pfr, a, 0, 0, 0);
            #pragma unroll
            for (int u = 0; u < 4; ++u) {
                const int c = mt * 16 + lq * 4 + u;
                __builtin_nontemporal_store(fmaxf(a[u], 0.f) * mf,
                                            awbase + ((long)c << 16) + pos);
            }
        }
    }
}

// ---------------------------------------------------------------------------
// K3: EXACT R7 kernel (measured 287 us). block = (n, c-quad), 48 KB LDS y
// tiles; per v-group-4: 12 broadcast ds_read_b128 + 4 coalesced 16B nt Aw
// loads -> 192 FMAs. In-place safe.
// ---------------------------------------------------------------------------
__global__ __launch_bounds__(256) void k3_einsum(
    const float* __restrict__ Aw, const float* __restrict__ y,
    float* __restrict__ out)
{
    __shared__ float ys[4][TT][VV];     // 48 KiB

    const int n   = blockIdx.x >> 4;
    const int c0  = (blockIdx.x & 15) * 4;
    const int tid = threadIdx.x;
    const int cq  = tid >> 6;           // 0..3 (wave-uniform)
    const int w4  = (tid & 63) * 4;     // 0..252

    {
        const float* src = y + ((long)(n * COUT + c0) * TT) * VV;
        float* dst = &ys[0][0][0];
        #pragma unroll
        for (int it = 0; it < 12; ++it) {
            const int idx = tid + it * 256;
            *reinterpret_cast<float4*>(dst + idx * 4) =
                *reinterpret_cast<const float4*>(src + idx * 4);
        }
    }
    __syncthreads();

    const float* awp = Aw + (((long)(n * COUT + c0 + cq)) << 16) + w4;
    float4 acc[TT];
    #pragma unroll
    for (int t = 0; t < TT; ++t) acc[t] = make_float4(0.f, 0.f, 0.f, 0.f);

    for (int v0 = 0; v0 < VV; v0 += 4) {
        float4 xs[TT];
        #pragma unroll
        for (int t = 0; t < TT; ++t)
            xs[t] = *reinterpret_cast<const float4*>(&ys[cq][t][v0]);

        const f32x4 aw0 = __builtin_nontemporal_load(
            reinterpret_cast<const f32x4*>(awp + (long)(v0 + 0) * VV));
        const f32x4 aw1 = __builtin_nontemporal_load(
            reinterpret_cast<const f32x4*>(awp + (long)(v0 + 1) * VV));
        const f32x4 aw2 = __builtin_nontemporal_load(
            reinterpret_cast<const f32x4*>(awp + (long)(v0 + 2) * VV));
        const f32x4 aw3 = __builtin_nontemporal_load(
            reinterpret_cast<const f32x4*>(awp + (long)(v0 + 3) * VV));

        #pragma unroll
        for (int t = 0; t < TT; ++t) {
            acc[t].x += xs[t].x * aw0.x + xs[t].y * aw1.x + xs[t].z * aw2.x + xs[t].w * aw3.x;
            acc[t].y += xs[t].x * aw0.y + xs[t].y * aw1.y + xs[t].z * aw2.y + xs[t].w * aw3.y;
            acc[t].z += xs[t].x * aw0.z + xs[t].y * aw1.z + xs[t].z * aw2.z + xs[t].w * aw3.z;
            acc[t].w += xs[t].x * aw0.w + xs[t].y * aw1.w + xs[t].z * aw2.w + xs[t].w * aw3.w;
        }
    }

    float* op = out + ((long)(n * COUT + c0 + cq) * TT) * VV + w4;
    #pragma unroll
    for (int t = 0; t < TT; ++t)
        *reinterpret_cast<float4*>(op + t * VV) = acc[t];
}

// ---------------------------------------------------------------------------
extern "C" void kernel_launch(void* const* d_in, const int* in_sizes, int n_in,
                              void* d_out, int out_size, void* d_ws, size_t ws_size,
                              hipStream_t stream)
{
    const float* x      = (const float*)d_in[0];
    const float* A      = (const float*)d_in[1];
    const float* conv_w = (const float*)d_in[2];
    const float* conv_b = (const float*)d_in[3];
    const float* w1     = (const float*)d_in[4];
    const float* b1     = (const float*)d_in[5];
    const float* w2     = (const float*)d_in[6];
    const float* b2     = (const float*)d_in[7];
    const float* w3     = (const float*)d_in[8];
    const float* b3     = (const float*)d_in[9];

    float* out = (float*)d_out;                                  // (64,64,12,256)
    float* Aw  = (float*)d_out + (long)NB * COUT * TT * VV;      // (64,64,256,256)
    const size_t y_bytes = (size_t)NB * COUT * TT * VV * sizeof(float);

    float* y = (ws_size >= y_bytes) ? (float*)d_ws : out;        // k3 handles alias

    // K1: conv -> y
    k1_conv<<<NB * TT, 256, 0, stream>>>(x, conv_w, conv_b, y);

    // K2: MLP + mask -> Aw (swapped-operand MFMA)
    k2_mlp<<<(NB * VSQ) / 256, 256, 0, stream>>>(A, w1, b1, w2, b2, w3, b3, Aw);

    // K3: einsum (in-place safe if y == out)
    k3_einsum<<<NB * (COUT / 4), 256, 0, stream>>>(Aw, y, out);
}

// Round 15
// 628.329 us; speedup vs baseline: 1.5198x; 1.0521x over previous
//
#include <hip/hip_runtime.h>
#include <hip/hip_bf16.h>

// Problem constants
#define NB   64      // batch N
#define TT   12      // T
#define VV   256     // V (vertices)
#define CIN  64
#define COUT 64
#define VSQ  65536   // V*V

typedef float f32x4 __attribute__((ext_vector_type(4)));

// ---------------------------------------------------------------------------
// K1: y[n,o,t,v] = sum_c x[n,c,t,v] * conv_w[o,c] + conv_b[o]
// block = (n*T + t), 256 threads (thread = v). Proven ~20 us (BW floor).
// ---------------------------------------------------------------------------
__global__ __launch_bounds__(256) void k1_conv(
    const float* __restrict__ x, const float* __restrict__ w,
    const float* __restrict__ b, float* __restrict__ y)
{
    const int nt = blockIdx.x;
    const int n  = nt / TT;
    const int t  = nt % TT;
    const int v  = threadIdx.x;

    const float* xp = x + ((long)n * CIN * TT + t) * VV + v;
    float xv[CIN];
    #pragma unroll 8
    for (int c = 0; c < CIN; ++c)
        xv[c] = xp[(long)c * TT * VV];          // coalesced

    float* yp = y + ((long)n * COUT * TT + t) * VV + v;

    for (int o0 = 0; o0 < COUT; o0 += 16) {
        float acc[16];
        #pragma unroll
        for (int i = 0; i < 16; ++i) acc[i] = b[o0 + i];
        #pragma unroll 8
        for (int c = 0; c < CIN; ++c) {
            const float xc = xv[c];
            #pragma unroll
            for (int i = 0; i < 16; ++i)
                acc[i] += w[(o0 + i) * CIN + c] * xc;   // uniform -> s_load
        }
        #pragma unroll
        for (int i = 0; i < 16; ++i)
            yp[(long)(o0 + i) * TT * VV] = acc[i];
    }
}

// ---------------------------------------------------------------------------
// K2: EXACT R7 variant (measured 324 us — best of all variants tried).
// 1 position/thread, o-chunks of 8, nontemporal stores, launch_bounds(256,5).
// R12/R14 attribution: K2 time is invariant (~330+-20) under weight-supply,
// occupancy, MFMA, and store-pattern restructuring — pattern/latency bound.
// ---------------------------------------------------------------------------
__global__ __launch_bounds__(256, 5) void k2_mlp(
    const float* __restrict__ A,
    const float* __restrict__ w1, const float* __restrict__ b1,
    const float* __restrict__ w2, const float* __restrict__ b2,
    const float* __restrict__ w3, const float* __restrict__ b3,
    float* __restrict__ Aw)
{
    const long idx = (long)blockIdx.x * 256 + threadIdx.x;  // n*VSQ + pos
    const int  n   = (int)(idx >> 16);
    const int  rem = (int)(idx & (VSQ - 1));

    const float* ap = A + ((long)n * 8 << 16) + rem;
    float f[7];
    #pragma unroll
    for (int c = 0; c < 7; ++c) f[c] = ap[(long)c << 16];
    const float m = ap[(long)7 << 16];

    float h1[16];
    #pragma unroll
    for (int o = 0; o < 16; ++o) {
        float acc = b1[o];
        #pragma unroll
        for (int k = 0; k < 7; ++k) acc += w1[o * 7 + k] * f[k];   // uniform
        h1[o] = fmaxf(acc, 0.f);
    }

    float h2[32];
    #pragma unroll
    for (int o = 0; o < 32; ++o) {
        float acc = b2[o];
        #pragma unroll
        for (int k = 0; k < 16; ++k) acc += w2[o * 16 + k] * h1[k]; // uniform
        h2[o] = fmaxf(acc, 0.f);
    }

    float* op = Aw + ((long)n * COUT << 16) + rem;
    for (int o0 = 0; o0 < 64; o0 += 8) {
        float acc[8];
        #pragma unroll
        for (int i = 0; i < 8; ++i) acc[i] = b3[o0 + i];
        #pragma unroll
        for (int k = 0; k < 32; ++k) {
            #pragma unroll
            for (int i = 0; i < 8; ++i)
                acc[i] += w3[(o0 + i) * 32 + k] * h2[k];            // uniform
        }
        #pragma unroll
        for (int i = 0; i < 8; ++i)
            __builtin_nontemporal_store(fmaxf(acc[i], 0.f) * m,
                                        op + ((long)(o0 + i) << 16));
    }
}

// ---------------------------------------------------------------------------
// K3 v3: R7 structure + (a) XCD-affinity bid remap: all 16 c-quad blocks of
// an n land on XCD n&7 in consecutive dispatch slots -> the 3.1 MB y-slab
// L2-resides per XCD (y's 200 MB re-read -> L2 hits); (b) v-step 8 with 8
// independent nontemporal f32x4 Aw loads in flight (8KB/wave) to close the
// 73%->~85% HBM gap if latency-limited. In-place safe (y reads complete
// before barrier; writes after).
// ---------------------------------------------------------------------------
__global__ __launch_bounds__(256) void k3_einsum(
    const float* __restrict__ Aw, const float* __restrict__ y,
    float* __restrict__ out)
{
    __shared__ float ys[4][TT][VV];     // 48 KiB

    const int g   = blockIdx.x;         // 0..1023
    const int n   = (g & 7) + 8 * (g >> 7);      // XCD-affinity: xcd = n&7
    const int c0  = ((g >> 3) & 15) * 4;
    const int tid = threadIdx.x;
    const int cq  = tid >> 6;           // 0..3 (wave-uniform)
    const int w4  = (tid & 63) * 4;     // 0..252

    // stage 4 y tiles: 3072 float4s, 12 per thread, coalesced
    {
        const float* src = y + ((long)(n * COUT + c0) * TT) * VV;
        float* dst = &ys[0][0][0];
        #pragma unroll
        for (int it = 0; it < 12; ++it) {
            const int idx = tid + it * 256;
            *reinterpret_cast<float4*>(dst + idx * 4) =
                *reinterpret_cast<const float4*>(src + idx * 4);
        }
    }
    __syncthreads();

    const float* awp = Aw + (((long)(n * COUT + c0 + cq)) << 16) + w4;
    f32x4 acc[TT];
    #pragma unroll
    for (int t = 0; t < TT; ++t) acc[t] = (f32x4)(0.f);

    for (int v0 = 0; v0 < VV; v0 += 8) {
        f32x4 aw[8];                    // 8 independent loads in flight
        #pragma unroll
        for (int i = 0; i < 8; ++i)
            aw[i] = __builtin_nontemporal_load(
                reinterpret_cast<const f32x4*>(awp + (long)(v0 + i) * VV));

        #pragma unroll
        for (int t = 0; t < TT; ++t) {
            const f32x4 x0 = *reinterpret_cast<const f32x4*>(&ys[cq][t][v0]);
            const f32x4 x1 = *reinterpret_cast<const f32x4*>(&ys[cq][t][v0 + 4]);
            acc[t] += x0.x * aw[0] + x0.y * aw[1] + x0.z * aw[2] + x0.w * aw[3]
                    + x1.x * aw[4] + x1.y * aw[5] + x1.z * aw[6] + x1.w * aw[7];
        }
    }

    float* op = out + ((long)(n * COUT + c0 + cq) * TT) * VV + w4;
    #pragma unroll
    for (int t = 0; t < TT; ++t)
        *reinterpret_cast<f32x4*>(op + t * VV) = acc[t];
}

// ---------------------------------------------------------------------------
extern "C" void kernel_launch(void* const* d_in, const int* in_sizes, int n_in,
                              void* d_out, int out_size, void* d_ws, size_t ws_size,
                              hipStream_t stream)
{
    const float* x      = (const float*)d_in[0];
    const float* A      = (const float*)d_in[1];
    const float* conv_w = (const float*)d_in[2];
    const float* conv_b = (const float*)d_in[3];
    const float* w1     = (const float*)d_in[4];
    const float* b1     = (const float*)d_in[5];
    const float* w2     = (const float*)d_in[6];
    const float* b2     = (const float*)d_in[7];
    const float* w3     = (const float*)d_in[8];
    const float* b3     = (const float*)d_in[9];

    float* out = (float*)d_out;                                  // (64,64,12,256)
    float* Aw  = (float*)d_out + (long)NB * COUT * TT * VV;      // (64,64,256,256)
    const size_t y_bytes = (size_t)NB * COUT * TT * VV * sizeof(float);

    float* y = (ws_size >= y_bytes) ? (float*)d_ws : out;        // k3 handles alias

    // K1: conv -> y
    k1_conv<<<NB * TT, 256, 0, stream>>>(x, conv_w, conv_b, y);

    // K2: MLP + mask -> Aw (R7 variant, best measured)
    k2_mlp<<<(NB * VSQ) / 256, 256, 0, stream>>>(A, w1, b1, w2, b2, w3, b3, Aw);

    // K3: einsum (XCD-affinity + deep load pipeline; in-place safe if y==out)
    k3_einsum<<<NB * (COUT / 4), 256, 0, stream>>>(Aw, y, out);
}

// Round 17
// 608.182 us; speedup vs baseline: 1.5702x; 1.0331x over previous
//
#include <hip/hip_runtime.h>
#include <hip/hip_bf16.h>

// Problem constants
#define NB   64      // batch N
#define TT   12      // T
#define VV   256     // V (vertices)
#define CIN  64
#define COUT 64
#define VSQ  65536   // V*V

typedef float f32x4 __attribute__((ext_vector_type(4)));

// ---------------------------------------------------------------------------
// K1: y[n,o,t,v] = sum_c x[n,c,t,v] * conv_w[o,c] + conv_b[o]
// block = (n*T + t), 256 threads (thread = v). Measured ~20 us (BW floor).
// ---------------------------------------------------------------------------
__global__ __launch_bounds__(256) void k1_conv(
    const float* __restrict__ x, const float* __restrict__ w,
    const float* __restrict__ b, float* __restrict__ y)
{
    const int nt = blockIdx.x;
    const int n  = nt / TT;
    const int t  = nt % TT;
    const int v  = threadIdx.x;

    const float* xp = x + ((long)n * CIN * TT + t) * VV + v;
    float xv[CIN];
    #pragma unroll 8
    for (int c = 0; c < CIN; ++c)
        xv[c] = xp[(long)c * TT * VV];          // coalesced

    float* yp = y + ((long)n * COUT * TT + t) * VV + v;

    for (int o0 = 0; o0 < COUT; o0 += 16) {
        float acc[16];
        #pragma unroll
        for (int i = 0; i < 16; ++i) acc[i] = b[o0 + i];
        #pragma unroll 8
        for (int c = 0; c < CIN; ++c) {
            const float xc = xv[c];
            #pragma unroll
            for (int i = 0; i < 16; ++i)
                acc[i] += w[(o0 + i) * CIN + c] * xc;   // uniform -> s_load
        }
        #pragma unroll
        for (int i = 0; i < 16; ++i)
            yp[(long)(o0 + i) * TT * VV] = acc[i];
    }
}

// ---------------------------------------------------------------------------
// K2: R7 variant (measured 324 us — best of all six variants tried).
// 1 position/thread, o-chunks of 8, nontemporal stores, launch_bounds(256,5).
// R12/R14 attribution: K2 time invariant (~330±20) under weight-supply,
// occupancy, MFMA, and store-pattern restructuring — pattern-bound at
// ~3.7 TB/s on the 64-plane (256KB-strided) write stream.
// ---------------------------------------------------------------------------
__global__ __launch_bounds__(256, 5) void k2_mlp(
    const float* __restrict__ A,
    const float* __restrict__ w1, const float* __restrict__ b1,
    const float* __restrict__ w2, const float* __restrict__ b2,
    const float* __restrict__ w3, const float* __restrict__ b3,
    float* __restrict__ Aw)
{
    const long idx = (long)blockIdx.x * 256 + threadIdx.x;  // n*VSQ + pos
    const int  n   = (int)(idx >> 16);
    const int  rem = (int)(idx & (VSQ - 1));

    const float* ap = A + ((long)n * 8 << 16) + rem;
    float f[7];
    #pragma unroll
    for (int c = 0; c < 7; ++c) f[c] = ap[(long)c << 16];
    const float m = ap[(long)7 << 16];

    float h1[16];
    #pragma unroll
    for (int o = 0; o < 16; ++o) {
        float acc = b1[o];
        #pragma unroll
        for (int k = 0; k < 7; ++k) acc += w1[o * 7 + k] * f[k];   // uniform
        h1[o] = fmaxf(acc, 0.f);
    }

    float h2[32];
    #pragma unroll
    for (int o = 0; o < 32; ++o) {
        float acc = b2[o];
        #pragma unroll
        for (int k = 0; k < 16; ++k) acc += w2[o * 16 + k] * h1[k]; // uniform
        h2[o] = fmaxf(acc, 0.f);
    }

    float* op = Aw + ((long)n * COUT << 16) + rem;
    for (int o0 = 0; o0 < 64; o0 += 8) {
        float acc[8];
        #pragma unroll
        for (int i = 0; i < 8; ++i) acc[i] = b3[o0 + i];
        #pragma unroll
        for (int k = 0; k < 32; ++k) {
            #pragma unroll
            for (int i = 0; i < 8; ++i)
                acc[i] += w3[(o0 + i) * 32 + k] * h2[k];            // uniform
        }
        #pragma unroll
        for (int i = 0; i < 8; ++i)
            __builtin_nontemporal_store(fmaxf(acc[i], 0.f) * m,
                                        op + ((long)(o0 + i) << 16));
    }
}

// ---------------------------------------------------------------------------
// K3: R15 variant (measured ~284 us — best of all four variants tried).
// block = (n, c-quad) with XCD-affinity remap (xcd = n&7 -> 3.1 MB y-slab
// L2-resident); 48 KB LDS y tiles; v-step 8 with 8 independent nontemporal
// f32x4 Aw loads in flight. Pattern-bound at ~4.6 TB/s. In-place safe
// (y reads complete before barrier; writes after).
// ---------------------------------------------------------------------------
__global__ __launch_bounds__(256) void k3_einsum(
    const float* __restrict__ Aw, const float* __restrict__ y,
    float* __restrict__ out)
{
    __shared__ float ys[4][TT][VV];     // 48 KiB

    const int g   = blockIdx.x;         // 0..1023
    const int n   = (g & 7) + 8 * (g >> 7);      // XCD-affinity: xcd = n&7
    const int c0  = ((g >> 3) & 15) * 4;
    const int tid = threadIdx.x;
    const int cq  = tid >> 6;           // 0..3 (wave-uniform)
    const int w4  = (tid & 63) * 4;     // 0..252

    // stage 4 y tiles: 3072 float4s, 12 per thread, coalesced
    {
        const float* src = y + ((long)(n * COUT + c0) * TT) * VV;
        float* dst = &ys[0][0][0];
        #pragma unroll
        for (int it = 0; it < 12; ++it) {
            const int idx = tid + it * 256;
            *reinterpret_cast<float4*>(dst + idx * 4) =
                *reinterpret_cast<const float4*>(src + idx * 4);
        }
    }
    __syncthreads();

    const float* awp = Aw + (((long)(n * COUT + c0 + cq)) << 16) + w4;
    f32x4 acc[TT];
    #pragma unroll
    for (int t = 0; t < TT; ++t) acc[t] = (f32x4)(0.f);

    for (int v0 = 0; v0 < VV; v0 += 8) {
        f32x4 aw[8];                    // 8 independent loads in flight
        #pragma unroll
        for (int i = 0; i < 8; ++i)
            aw[i] = __builtin_nontemporal_load(
                reinterpret_cast<const f32x4*>(awp + (long)(v0 + i) * VV));

        #pragma unroll
        for (int t = 0; t < TT; ++t) {
            const f32x4 x0 = *reinterpret_cast<const f32x4*>(&ys[cq][t][v0]);
            const f32x4 x1 = *reinterpret_cast<const f32x4*>(&ys[cq][t][v0 + 4]);
            acc[t] += x0.x * aw[0] + x0.y * aw[1] + x0.z * aw[2] + x0.w * aw[3]
                    + x1.x * aw[4] + x1.y * aw[5] + x1.z * aw[6] + x1.w * aw[7];
        }
    }

    float* op = out + ((long)(n * COUT + c0 + cq) * TT) * VV + w4;
    #pragma unroll
    for (int t = 0; t < TT; ++t)
        *reinterpret_cast<f32x4*>(op + t * VV) = acc[t];
}

// ---------------------------------------------------------------------------
extern "C" void kernel_launch(void* const* d_in, const int* in_sizes, int n_in,
                              void* d_out, int out_size, void* d_ws, size_t ws_size,
                              hipStream_t stream)
{
    const float* x      = (const float*)d_in[0];
    const float* A      = (const float*)d_in[1];
    const float* conv_w = (const float*)d_in[2];
    const float* conv_b = (const float*)d_in[3];
    const float* w1     = (const float*)d_in[4];
    const float* b1     = (const float*)d_in[5];
    const float* w2     = (const float*)d_in[6];
    const float* b2     = (const float*)d_in[7];
    const float* w3     = (const float*)d_in[8];
    const float* b3     = (const float*)d_in[9];

    float* out = (float*)d_out;                                  // (64,64,12,256)
    float* Aw  = (float*)d_out + (long)NB * COUT * TT * VV;      // (64,64,256,256)
    const size_t y_bytes = (size_t)NB * COUT * TT * VV * sizeof(float);

    float* y = (ws_size >= y_bytes) ? (float*)d_ws : out;        // k3 handles alias

    // K1: conv -> y
    k1_conv<<<NB * TT, 256, 0, stream>>>(x, conv_w, conv_b, y);

    // K2: MLP + mask -> Aw (best measured variant)
    k2_mlp<<<(NB * VSQ) / 256, 256, 0, stream>>>(A, w1, b1, w2, b2, w3, b3, Aw);

    // K3: einsum (XCD-affinity + deep load pipeline; in-place safe if y==out)
    k3_einsum<<<NB * (COUT / 4), 256, 0, stream>>>(Aw, y, out);
}